// Round 3
// baseline (15832.608 us; speedup 1.0000x reference)
//
#include <hip/hip_runtime.h>
#include <hip/hip_cooperative_groups.h>

namespace cg = cooperative_groups;

#define N_NODES 4096
#define H_DIM 32
#define F_INPUT 5
#define ROLLS 200
#define NBLOCKS 256
#define NTHREADS 512
#define A_STRIDE 4104   // 4096 + 8-element pad

// dynamic-LDS byte offsets (all 16B-aligned)
#define OFF_AS   0                  // A-slice bf16: 16 x 4104 x 2 = 131328
#define OFF_RED  131328             // split-K partials 8x16x33 f32 = 16896 (aliased by gatesLds 16x132 f32)
#define OFF_INPB 148224             // 16x48 bf16 = 1536
#define OFF_HB   149760
#define OFF_HNB  151296
#define OFF_CNB  152832
#define OFF_XL   154368             // 16x8 f32 = 512
#define LDS_TOTAL 154880

typedef __attribute__((ext_vector_type(8))) short bf16x8;
typedef __attribute__((ext_vector_type(4))) float fx4;
typedef __attribute__((ext_vector_type(4))) unsigned short us4;

__device__ __forceinline__ unsigned short f2bf(float f) {
  unsigned int u = __builtin_bit_cast(unsigned int, f);
  u += 0x7fffu + ((u >> 16) & 1u);   // RNE; inputs benign (no NaN/inf)
  return (unsigned short)(u >> 16);
}

// ---- setup kernel (kernel-boundary visibility for all one-time data) ----
__global__ void k_init(const float* __restrict__ X, const float* __restrict__ Wx,
                       const float* __restrict__ Wih, const float* __restrict__ Whh,
                       const float* __restrict__ Wh, const float* __restrict__ Wc,
                       unsigned short* __restrict__ Mt0,
                       unsigned short* __restrict__ WihB, unsigned short* __restrict__ WhhB,
                       unsigned short* __restrict__ WhT, unsigned short* __restrict__ WcT) {
  int idx = blockIdx.x * 256 + threadIdx.x;      // grid 512*256 = 131072 = N*H exactly
  int k = idx >> 12;         // 0..31
  int row = idx & 4095;
  float s = 0.f;
#pragma unroll
  for (int f = 0; f < F_INPUT; ++f) s += X[row * F_INPUT + f] * Wx[f * H_DIM + k];
  Mt0[(size_t)k * N_NODES + row] = f2bf(s);
  if (idx < 4096) { WihB[idx] = f2bf(Wih[idx]); WhhB[idx] = f2bf(Whh[idx]); }
  if (idx < 1024) {
    int a = idx >> 5, b = idx & 31;
    WhT[a * 32 + b] = f2bf(Wh[b * 32 + a]);   // WhT[n][j] = Wh[j][n]
    WcT[a * 32 + b] = f2bf(Wc[b * 32 + a]);
  }
}

__global__ __launch_bounds__(NTHREADS, 2) void k_persist(
    const float* __restrict__ X, const float* __restrict__ A,
    const float* __restrict__ Wx,
    const float* __restrict__ b_ih, const float* __restrict__ b_hh,
    const float* __restrict__ Wfc, const float* __restrict__ b_fc,
    float* __restrict__ out,
    unsigned short* __restrict__ Mt0, unsigned short* __restrict__ Mt1,
    const unsigned short* __restrict__ WihB, const unsigned short* __restrict__ WhhB,
    const unsigned short* __restrict__ WhT, const unsigned short* __restrict__ WcT) {

  extern __shared__ char smem[];
  unsigned short* As   = (unsigned short*)(smem + OFF_AS);
  float* red           = (float*)(smem + OFF_RED);
  float* gatesLds      = (float*)(smem + OFF_RED);   // alias: red dead once inpB written
  unsigned short* inpB = (unsigned short*)(smem + OFF_INPB);
  unsigned short* hB   = (unsigned short*)(smem + OFF_HB);
  unsigned short* hnB  = (unsigned short*)(smem + OFF_HNB);
  unsigned short* cnB  = (unsigned short*)(smem + OFF_CNB);
  float* xLds          = (float*)(smem + OFF_XL);

  cg::grid_group grid = cg::this_grid();

  const int tid  = threadIdx.x;
  const int wave = tid >> 6;
  const int lane = tid & 63;
  const int l15  = lane & 15;
  const int quad = lane >> 4;
  const int row0 = blockIdx.x << 4;
  const int rr   = tid >> 5;     // 0..15
  const int kk_  = tid & 31;     // 0..31

  // ---- phase 0: stage A-slice -> LDS bf16 (block-local; no cross-block deps) ----
  {
    const fx4* Arow = (const fx4*)(A + (size_t)row0 * N_NODES);
    for (int i = tid; i < 16 * (N_NODES / 4); i += NTHREADS) {
      fx4 v = Arow[i];
      us4 o; o.x = f2bf(v.x); o.y = f2bf(v.y); o.z = f2bf(v.z); o.w = f2bf(v.w);
      int r = i >> 10, c = (i & 1023) << 2;
      *(us4*)(As + r * A_STRIDE + c) = o;
    }
  }
  float h_reg = 0.f, c_reg = 0.f;
  __syncthreads();

  for (int t = 0; t < ROLLS; ++t) {
    const unsigned short* Mi = (t & 1) ? Mt1 : Mt0;
    unsigned short* Mo       = (t & 1) ? Mt0 : Mt1;

    hB[rr * 48 + kk_] = f2bf(h_reg);
    if (t + 1 < ROLLS && tid < 128) {
      int r2 = tid >> 3, f = tid & 7;
      if (f < F_INPUT)
        xLds[r2 * 8 + f] = X[(size_t)(t + 1) * N_NODES * F_INPUT + (size_t)(row0 + r2) * F_INPUT + f];
    }

    // ---- split-K MFMA: inp(16x32) = A(16x4096)@M(4096x32); wave w owns K-chunk 512 ----
    fx4 acc0 = {0.f,0.f,0.f,0.f}, acc1 = {0.f,0.f,0.f,0.f};
    {
      const unsigned short* Al = As + l15 * A_STRIDE + wave * 512 + quad * 8;
      const unsigned short* B0 = Mi + (size_t)l15 * N_NODES        + wave * 512 + quad * 8;
      const unsigned short* B1 = Mi + (size_t)(16 + l15) * N_NODES + wave * 512 + quad * 8;
#pragma unroll
      for (int kk = 0; kk < 16; ++kk) {
        bf16x8 a  = *(const bf16x8*)(Al + kk * 32);
        bf16x8 b0 = *(const bf16x8*)(B0 + kk * 32);
        bf16x8 b1 = *(const bf16x8*)(B1 + kk * 32);
        acc0 = __builtin_amdgcn_mfma_f32_16x16x32_bf16(a, b0, acc0, 0, 0, 0);
        acc1 = __builtin_amdgcn_mfma_f32_16x16x32_bf16(a, b1, acc1, 0, 0, 0);
      }
    }
#pragma unroll
    for (int r = 0; r < 4; ++r) {   // C-layout: row = quad*4+r, col = l15
      red[(wave * 16 + quad * 4 + r) * 33 + l15]      = acc0[r];
      red[(wave * 16 + quad * 4 + r) * 33 + 16 + l15] = acc1[r];
    }
    __syncthreads();

    // reduce 8 partials -> inp bf16 (A-frag layout)
    {
      float s = 0.f;
#pragma unroll
      for (int w = 0; w < 8; ++w) s += red[(w * 16 + rr) * 33 + kk_];
      inpB[rr * 48 + kk_] = f2bf(s);
    }
    __syncthreads();

    // ---- gates(16x128) = inp@Wih^T + h@Whh^T + b; wave w owns gate cols [16w,16w+16) ----
    {
      int g = (wave << 4) + l15;
      bf16x8 aI = *(const bf16x8*)(inpB + l15 * 48 + quad * 8);
      bf16x8 aH = *(const bf16x8*)(hB   + l15 * 48 + quad * 8);
      bf16x8 bI = *(const bf16x8*)(WihB + g * 32 + quad * 8);
      bf16x8 bH = *(const bf16x8*)(WhhB + g * 32 + quad * 8);
      fx4 gacc = {0.f,0.f,0.f,0.f};
      gacc = __builtin_amdgcn_mfma_f32_16x16x32_bf16(aI, bI, gacc, 0, 0, 0);
      gacc = __builtin_amdgcn_mfma_f32_16x16x32_bf16(aH, bH, gacc, 0, 0, 0);
      float bias = b_ih[g] + b_hh[g];
#pragma unroll
      for (int r = 0; r < 4; ++r) gatesLds[(quad * 4 + r) * 132 + g] = gacc[r] + bias;
    }
    __syncthreads();

    // ---- LSTM cell elementwise; state in registers ----
    {
      float gi = gatesLds[rr * 132 + kk_];
      float gf = gatesLds[rr * 132 + 32 + kk_];
      float gg = gatesLds[rr * 132 + 64 + kk_];
      float go = gatesLds[rr * 132 + 96 + kk_];
      float i_ = 1.f / (1.f + __expf(-gi));
      float f_ = 1.f / (1.f + __expf(-gf));
      float g_ = tanhf(gg);
      float o_ = 1.f / (1.f + __expf(-go));
      float cn = f_ * c_reg + i_ * g_;
      float hn = o_ * tanhf(cn);
      c_reg = cn; h_reg = hn;
      hnB[rr * 48 + kk_] = f2bf(hn);
      cnB[rr * 48 + kk_] = f2bf(cn);
    }
    if (t == ROLLS - 1) break;
    __syncthreads();

    // ---- M_next = h_new@Wh + c_new@Wc + x@Wx; waves 0-1, direct global us4 store ----
    if (wave < 2) {
      int n = (wave << 4) + l15;
      bf16x8 aH = *(const bf16x8*)(hnB + l15 * 48 + quad * 8);
      bf16x8 aC = *(const bf16x8*)(cnB + l15 * 48 + quad * 8);
      bf16x8 bH = *(const bf16x8*)(WhT + n * 32 + quad * 8);
      bf16x8 bC = *(const bf16x8*)(WcT + n * 32 + quad * 8);
      fx4 m4 = {0.f,0.f,0.f,0.f};
      m4 = __builtin_amdgcn_mfma_f32_16x16x32_bf16(aH, bH, m4, 0, 0, 0);
      m4 = __builtin_amdgcn_mfma_f32_16x16x32_bf16(aC, bC, m4, 0, 0, 0);
      us4 o;
#pragma unroll
      for (int r = 0; r < 4; ++r) {
        int m = quad * 4 + r;
        float xs = m4[r];
#pragma unroll
        for (int f = 0; f < F_INPUT; ++f) xs += xLds[m * 8 + f] * Wx[f * H_DIM + n];
        o[r] = f2bf(xs);
      }
      *(us4*)(Mo + (size_t)n * N_NODES + row0 + quad * 4) = o;   // Mt[n][row0+m]
    }

    // ---- cross-XCD handoff: device-scope release -> grid barrier -> device-scope acquire ----
    __builtin_amdgcn_fence(__ATOMIC_RELEASE, "agent");   // writeback dirty Mo lines (L2 -> coherent point)
    grid.sync();
    __builtin_amdgcn_fence(__ATOMIC_ACQUIRE, "agent");   // invalidate L1/L2 so Mi reads see fresh data
  }

  // ---- final: out = h @ Wfc^T + b_fc ----
  {
    float v = h_reg * Wfc[kk_];
    v += __shfl_xor(v, 16);
    v += __shfl_xor(v, 8);
    v += __shfl_xor(v, 4);
    v += __shfl_xor(v, 2);
    v += __shfl_xor(v, 1);
    if (kk_ == 0) out[row0 + rr] = v + b_fc[0];
  }
}

extern "C" void kernel_launch(void* const* d_in, const int* in_sizes, int n_in,
                              void* d_out, int out_size, void* d_ws, size_t ws_size,
                              hipStream_t stream) {
  (void)in_sizes; (void)n_in; (void)out_size; (void)ws_size;
  const float* X   = (const float*)d_in[0];
  const float* A   = (const float*)d_in[1];
  const float* Wx  = (const float*)d_in[2];
  const float* Wh  = (const float*)d_in[3];
  const float* Wc  = (const float*)d_in[4];
  const float* Wih = (const float*)d_in[5];
  const float* Whh = (const float*)d_in[6];
  const float* bih = (const float*)d_in[7];
  const float* bhh = (const float*)d_in[8];
  const float* Wfc = (const float*)d_in[9];
  const float* bfc = (const float*)d_in[10];
  float* out = (float*)d_out;

  char* ws = (char*)d_ws;
  unsigned short* Mt0  = (unsigned short*)ws; ws += (size_t)N_NODES * H_DIM * 2;
  unsigned short* Mt1  = (unsigned short*)ws; ws += (size_t)N_NODES * H_DIM * 2;
  unsigned short* WihB = (unsigned short*)ws; ws += 128 * 32 * 2;
  unsigned short* WhhB = (unsigned short*)ws; ws += 128 * 32 * 2;
  unsigned short* WhT  = (unsigned short*)ws; ws += 32 * 32 * 2;
  unsigned short* WcT  = (unsigned short*)ws; ws += 32 * 32 * 2;

  hipLaunchKernelGGL(k_init, dim3(512), dim3(256), 0, stream,
                     X, Wx, Wih, Whh, Wh, Wc, Mt0, WihB, WhhB, WhT, WcT);

  hipFuncSetAttribute((const void*)k_persist,
                      hipFuncAttributeMaxDynamicSharedMemorySize, LDS_TOTAL);

  void* args[] = {
    (void*)&X, (void*)&A, (void*)&Wx,
    (void*)&bih, (void*)&bhh, (void*)&Wfc, (void*)&bfc, (void*)&out,
    (void*)&Mt0, (void*)&Mt1, (void*)&WihB, (void*)&WhhB, (void*)&WhT, (void*)&WcT
  };
  hipLaunchCooperativeKernel((const void*)k_persist, dim3(NBLOCKS), dim3(NTHREADS),
                             args, LDS_TOTAL, stream);
}

// Round 4
// 4904.899 us; speedup vs baseline: 3.2279x; 3.2279x over previous
//
#include <hip/hip_runtime.h>

#define N_NODES 4096
#define H_DIM 32
#define F_INPUT 5
#define ROLLS 200
#define NBLOCKS 256
#define NTHREADS 512
#define A_STRIDE 4104   // 4096 + 8-element pad

// dynamic-LDS byte offsets (all 16B-aligned)
#define OFF_AS   0                  // A-slice bf16: 16 x 4104 x 2 = 131328
#define OFF_RED  131328             // split-K partials 8x16x33 f32 = 16896 (aliased by gatesLds 16x132 f32)
#define OFF_INPB 148224             // 16x48 bf16 = 1536
#define OFF_HB   149760
#define OFF_HNB  151296
#define OFF_CNB  152832
#define OFF_XL   154368             // 16x8 f32 = 512
#define LDS_TOTAL 154880

typedef __attribute__((ext_vector_type(8))) short bf16x8;
typedef __attribute__((ext_vector_type(4))) float fx4;
typedef __attribute__((ext_vector_type(4))) unsigned short us4;

__device__ __forceinline__ unsigned short f2bf(float f) {
  unsigned int u = __builtin_bit_cast(unsigned int, f);
  u += 0x7fffu + ((u >> 16) & 1u);   // RNE; inputs benign (no NaN/inf)
  return (unsigned short)(u >> 16);
}

// ---- setup kernel (kernel-boundary visibility for all one-time data) ----
__global__ void k_init(const float* __restrict__ X, const float* __restrict__ Wx,
                       const float* __restrict__ Wih, const float* __restrict__ Whh,
                       const float* __restrict__ Wh, const float* __restrict__ Wc,
                       unsigned short* __restrict__ Mt0,
                       unsigned short* __restrict__ WihB, unsigned short* __restrict__ WhhB,
                       unsigned short* __restrict__ WhT, unsigned short* __restrict__ WcT,
                       unsigned int* __restrict__ bar) {
  int idx = blockIdx.x * 256 + threadIdx.x;      // grid 512*256 = 131072 = N*H exactly
  int k = idx >> 12;         // 0..31
  int row = idx & 4095;
  float s = 0.f;
#pragma unroll
  for (int f = 0; f < F_INPUT; ++f) s += X[row * F_INPUT + f] * Wx[f * H_DIM + k];
  Mt0[(size_t)k * N_NODES + row] = f2bf(s);
  if (idx < 4096) { WihB[idx] = f2bf(Wih[idx]); WhhB[idx] = f2bf(Whh[idx]); }
  if (idx < 1024) {
    int a = idx >> 5, b = idx & 31;
    WhT[a * 32 + b] = f2bf(Wh[b * 32 + a]);   // WhT[n][j] = Wh[j][n]
    WcT[a * 32 + b] = f2bf(Wc[b * 32 + a]);
  }
  if (idx < 32) bar[idx] = 0u;     // zero barrier line every call (ws is re-poisoned)
}

__global__ __launch_bounds__(NTHREADS, 2) void k_persist(
    const float* __restrict__ X, const float* __restrict__ A,
    const float* __restrict__ Wx,
    const float* __restrict__ b_ih, const float* __restrict__ b_hh,
    const float* __restrict__ Wfc, const float* __restrict__ b_fc,
    float* __restrict__ out,
    unsigned short* __restrict__ Mt0, unsigned short* __restrict__ Mt1,
    const unsigned short* __restrict__ WihB, const unsigned short* __restrict__ WhhB,
    const unsigned short* __restrict__ WhT, const unsigned short* __restrict__ WcT,
    unsigned int* __restrict__ bar) {

  extern __shared__ char smem[];
  unsigned short* As   = (unsigned short*)(smem + OFF_AS);
  float* red           = (float*)(smem + OFF_RED);
  float* gatesLds      = (float*)(smem + OFF_RED);   // alias: red dead once inpB written
  unsigned short* inpB = (unsigned short*)(smem + OFF_INPB);
  unsigned short* hB   = (unsigned short*)(smem + OFF_HB);
  unsigned short* hnB  = (unsigned short*)(smem + OFF_HNB);
  unsigned short* cnB  = (unsigned short*)(smem + OFF_CNB);
  float* xLds          = (float*)(smem + OFF_XL);

  const int tid  = threadIdx.x;
  const int wave = tid >> 6;
  const int lane = tid & 63;
  const int l15  = lane & 15;
  const int quad = lane >> 4;
  const int row0 = blockIdx.x << 4;
  const int rr   = tid >> 5;     // 0..15
  const int kk_  = tid & 31;     // 0..31

  // ---- phase 0: stage A-slice -> LDS bf16 (block-local) ----
  {
    const fx4* Arow = (const fx4*)(A + (size_t)row0 * N_NODES);
    for (int i = tid; i < 16 * (N_NODES / 4); i += NTHREADS) {
      fx4 v = Arow[i];
      us4 o; o.x = f2bf(v.x); o.y = f2bf(v.y); o.z = f2bf(v.z); o.w = f2bf(v.w);
      int r = i >> 10, c = (i & 1023) << 2;
      *(us4*)(As + r * A_STRIDE + c) = o;
    }
  }
  float h_reg = 0.f, c_reg = 0.f;
  __syncthreads();

  for (int t = 0; t < ROLLS; ++t) {
    const unsigned short* Mi = (t & 1) ? Mt1 : Mt0;
    unsigned short* Mo       = (t & 1) ? Mt0 : Mt1;

    hB[rr * 48 + kk_] = f2bf(h_reg);
    if (t + 1 < ROLLS && tid < 128) {
      int r2 = tid >> 3, f = tid & 7;
      if (f < F_INPUT)
        xLds[r2 * 8 + f] = X[(size_t)(t + 1) * N_NODES * F_INPUT + (size_t)(row0 + r2) * F_INPUT + f];
    }

    // ---- split-K MFMA: inp(16x32) = A(16x4096)@M(4096x32); wave w owns K-chunk 512 ----
    fx4 acc0 = {0.f,0.f,0.f,0.f}, acc1 = {0.f,0.f,0.f,0.f};
    {
      const unsigned short* Al = As + l15 * A_STRIDE + wave * 512 + quad * 8;
      const unsigned short* B0 = Mi + (size_t)l15 * N_NODES        + wave * 512 + quad * 8;
      const unsigned short* B1 = Mi + (size_t)(16 + l15) * N_NODES + wave * 512 + quad * 8;
#pragma unroll
      for (int kk = 0; kk < 16; ++kk) {
        bf16x8 a  = *(const bf16x8*)(Al + kk * 32);
        bf16x8 b0 = *(const bf16x8*)(B0 + kk * 32);
        bf16x8 b1 = *(const bf16x8*)(B1 + kk * 32);
        acc0 = __builtin_amdgcn_mfma_f32_16x16x32_bf16(a, b0, acc0, 0, 0, 0);
        acc1 = __builtin_amdgcn_mfma_f32_16x16x32_bf16(a, b1, acc1, 0, 0, 0);
      }
    }
#pragma unroll
    for (int r = 0; r < 4; ++r) {   // C-layout: row = quad*4+r, col = l15
      red[(wave * 16 + quad * 4 + r) * 33 + l15]      = acc0[r];
      red[(wave * 16 + quad * 4 + r) * 33 + 16 + l15] = acc1[r];
    }
    __syncthreads();

    // reduce 8 partials -> inp bf16 (A-frag layout)
    {
      float s = 0.f;
#pragma unroll
      for (int w = 0; w < 8; ++w) s += red[(w * 16 + rr) * 33 + kk_];
      inpB[rr * 48 + kk_] = f2bf(s);
    }
    __syncthreads();

    // ---- gates(16x128) = inp@Wih^T + h@Whh^T + b; wave w owns gate cols [16w,16w+16) ----
    {
      int g = (wave << 4) + l15;
      bf16x8 aI = *(const bf16x8*)(inpB + l15 * 48 + quad * 8);
      bf16x8 aH = *(const bf16x8*)(hB   + l15 * 48 + quad * 8);
      bf16x8 bI = *(const bf16x8*)(WihB + g * 32 + quad * 8);
      bf16x8 bH = *(const bf16x8*)(WhhB + g * 32 + quad * 8);
      fx4 gacc = {0.f,0.f,0.f,0.f};
      gacc = __builtin_amdgcn_mfma_f32_16x16x32_bf16(aI, bI, gacc, 0, 0, 0);
      gacc = __builtin_amdgcn_mfma_f32_16x16x32_bf16(aH, bH, gacc, 0, 0, 0);
      float bias = b_ih[g] + b_hh[g];
#pragma unroll
      for (int r = 0; r < 4; ++r) gatesLds[(quad * 4 + r) * 132 + g] = gacc[r] + bias;
    }
    __syncthreads();

    // ---- LSTM cell elementwise; state in registers ----
    {
      float gi = gatesLds[rr * 132 + kk_];
      float gf = gatesLds[rr * 132 + 32 + kk_];
      float gg = gatesLds[rr * 132 + 64 + kk_];
      float go = gatesLds[rr * 132 + 96 + kk_];
      float i_ = 1.f / (1.f + __expf(-gi));
      float f_ = 1.f / (1.f + __expf(-gf));
      float g_ = tanhf(gg);
      float o_ = 1.f / (1.f + __expf(-go));
      float cn = f_ * c_reg + i_ * g_;
      float hn = o_ * tanhf(cn);
      c_reg = cn; h_reg = hn;
      hnB[rr * 48 + kk_] = f2bf(hn);
      cnB[rr * 48 + kk_] = f2bf(cn);
    }
    if (t == ROLLS - 1) break;
    __syncthreads();

    // ---- M_next = h_new@Wh + c_new@Wc + x@Wx; waves 0-1, direct global us4 store ----
    if (wave < 2) {
      int n = (wave << 4) + l15;
      bf16x8 aH = *(const bf16x8*)(hnB + l15 * 48 + quad * 8);
      bf16x8 aC = *(const bf16x8*)(cnB + l15 * 48 + quad * 8);
      bf16x8 bH = *(const bf16x8*)(WhT + n * 32 + quad * 8);
      bf16x8 bC = *(const bf16x8*)(WcT + n * 32 + quad * 8);
      fx4 m4 = {0.f,0.f,0.f,0.f};
      m4 = __builtin_amdgcn_mfma_f32_16x16x32_bf16(aH, bH, m4, 0, 0, 0);
      m4 = __builtin_amdgcn_mfma_f32_16x16x32_bf16(aC, bC, m4, 0, 0, 0);
      us4 o;
#pragma unroll
      for (int r = 0; r < 4; ++r) {
        int m = quad * 4 + r;
        float xs = m4[r];
#pragma unroll
        for (int f = 0; f < F_INPUT; ++f) xs += xLds[m * 8 + f] * Wx[f * H_DIM + n];
        o[r] = f2bf(xs);
      }
      *(us4*)(Mo + (size_t)n * N_NODES + row0 + quad * 4) = o;   // Mt[n][row0+m]
    }

    // ---- lightweight grid barrier with single wbl2/inv per block ----
    __syncthreads();   // drains every wave's Mo stores to L2 (vmcnt(0) before s_barrier)
    if (tid == 0) {
      __builtin_amdgcn_fence(__ATOMIC_RELEASE, "agent");           // one buffer_wbl2
      __hip_atomic_fetch_add(bar, 1u, __ATOMIC_RELAXED, __HIP_MEMORY_SCOPE_AGENT);
      const unsigned int target = (unsigned int)NBLOCKS * (unsigned int)(t + 1);
      while (__hip_atomic_load(bar, __ATOMIC_RELAXED, __HIP_MEMORY_SCOPE_AGENT) < target)
        __builtin_amdgcn_s_sleep(1);
      __builtin_amdgcn_fence(__ATOMIC_ACQUIRE, "agent");           // one buffer_inv
    }
    __syncthreads();
  }

  // ---- final: out = h @ Wfc^T + b_fc ----
  {
    float v = h_reg * Wfc[kk_];
    v += __shfl_xor(v, 16);
    v += __shfl_xor(v, 8);
    v += __shfl_xor(v, 4);
    v += __shfl_xor(v, 2);
    v += __shfl_xor(v, 1);
    if (kk_ == 0) out[row0 + rr] = v + b_fc[0];
  }
}

extern "C" void kernel_launch(void* const* d_in, const int* in_sizes, int n_in,
                              void* d_out, int out_size, void* d_ws, size_t ws_size,
                              hipStream_t stream) {
  (void)in_sizes; (void)n_in; (void)out_size; (void)ws_size;
  const float* X   = (const float*)d_in[0];
  const float* A   = (const float*)d_in[1];
  const float* Wx  = (const float*)d_in[2];
  const float* Wh  = (const float*)d_in[3];
  const float* Wc  = (const float*)d_in[4];
  const float* Wih = (const float*)d_in[5];
  const float* Whh = (const float*)d_in[6];
  const float* bih = (const float*)d_in[7];
  const float* bhh = (const float*)d_in[8];
  const float* Wfc = (const float*)d_in[9];
  const float* bfc = (const float*)d_in[10];
  float* out = (float*)d_out;

  char* ws = (char*)d_ws;
  unsigned short* Mt0  = (unsigned short*)ws; ws += (size_t)N_NODES * H_DIM * 2;
  unsigned short* Mt1  = (unsigned short*)ws; ws += (size_t)N_NODES * H_DIM * 2;
  unsigned short* WihB = (unsigned short*)ws; ws += 128 * 32 * 2;
  unsigned short* WhhB = (unsigned short*)ws; ws += 128 * 32 * 2;
  unsigned short* WhT  = (unsigned short*)ws; ws += 32 * 32 * 2;
  unsigned short* WcT  = (unsigned short*)ws; ws += 32 * 32 * 2;
  ws = (char*)(((size_t)ws + 255) & ~(size_t)255);
  unsigned int* bar    = (unsigned int*)ws;   ws += 128;

  hipLaunchKernelGGL(k_init, dim3(512), dim3(256), 0, stream,
                     X, Wx, Wih, Whh, Wh, Wc, Mt0, WihB, WhhB, WhT, WcT, bar);

  hipFuncSetAttribute((const void*)k_persist,
                      hipFuncAttributeMaxDynamicSharedMemorySize, LDS_TOTAL);

  void* args[] = {
    (void*)&X, (void*)&A, (void*)&Wx,
    (void*)&bih, (void*)&bhh, (void*)&Wfc, (void*)&bfc, (void*)&out,
    (void*)&Mt0, (void*)&Mt1, (void*)&WihB, (void*)&WhhB, (void*)&WhT, (void*)&WcT,
    (void*)&bar
  };
  hipLaunchCooperativeKernel((const void*)k_persist, dim3(NBLOCKS), dim3(NTHREADS),
                             args, LDS_TOTAL, stream);
}

// Round 5
// 4198.191 us; speedup vs baseline: 3.7713x; 1.1683x over previous
//
#include <hip/hip_runtime.h>

#define N_NODES 4096
#define H_DIM 32
#define F_INPUT 5
#define ROLLS 200
#define NBLOCKS 256
#define NTHREADS 512
#define A_STRIDE 4104   // 4096 + 8-element pad

// dynamic-LDS byte offsets (all 16B-aligned)
#define OFF_AS   0                  // A-slice bf16: 16 x 4104 x 2 = 131328
#define OFF_RED  131328             // split-K partials 8x16x33 f32 = 16896 (aliased by gatesLds 16x132 f32)
#define OFF_INPB 148224             // 16x48 bf16 = 1536
#define OFF_HB   149760
#define OFF_HNB  151296
#define OFF_CNB  152832
#define OFF_XL   154368             // 16x8 f32 = 512
#define LDS_TOTAL 154880

// barrier layout in uints (128B stride per flag line)
#define BAR_ARRIVE(b) ((b) * 32)
#define BAR_GO(g)     ((NBLOCKS + (g)) * 32)
#define BAR_UINTS     ((NBLOCKS + 8) * 32)

typedef __attribute__((ext_vector_type(8))) short bf16x8;
typedef __attribute__((ext_vector_type(4))) float fx4;
typedef __attribute__((ext_vector_type(4))) unsigned short us4;

__device__ __forceinline__ unsigned short f2bf(float f) {
  unsigned int u = __builtin_bit_cast(unsigned int, f);
  u += 0x7fffu + ((u >> 16) & 1u);   // RNE; inputs benign (no NaN/inf)
  return (unsigned short)(u >> 16);
}

// ---- setup kernel (kernel-boundary visibility for all one-time data) ----
__global__ void k_init(const float* __restrict__ X, const float* __restrict__ Wx,
                       const float* __restrict__ Wih, const float* __restrict__ Whh,
                       const float* __restrict__ Wh, const float* __restrict__ Wc,
                       unsigned short* __restrict__ Mt0,
                       unsigned short* __restrict__ WihB, unsigned short* __restrict__ WhhB,
                       unsigned short* __restrict__ WhT, unsigned short* __restrict__ WcT,
                       unsigned int* __restrict__ bar) {
  int idx = blockIdx.x * 256 + threadIdx.x;      // grid 512*256 = 131072 = N*H exactly
  int k = idx >> 12;         // 0..31
  int row = idx & 4095;
  float s = 0.f;
#pragma unroll
  for (int f = 0; f < F_INPUT; ++f) s += X[row * F_INPUT + f] * Wx[f * H_DIM + k];
  Mt0[(size_t)k * N_NODES + row] = f2bf(s);
  if (idx < 4096) { WihB[idx] = f2bf(Wih[idx]); WhhB[idx] = f2bf(Whh[idx]); }
  if (idx < 1024) {
    int a = idx >> 5, b = idx & 31;
    WhT[a * 32 + b] = f2bf(Wh[b * 32 + a]);   // WhT[n][j] = Wh[j][n]
    WcT[a * 32 + b] = f2bf(Wc[b * 32 + a]);
  }
  if (idx < BAR_UINTS) bar[idx] = 0u;     // zero all flag lines every call (ws re-poisoned)
}

__global__ __launch_bounds__(NTHREADS, 2) void k_persist(
    const float* __restrict__ X, const float* __restrict__ A,
    const float* __restrict__ Wx,
    const float* __restrict__ b_ih, const float* __restrict__ b_hh,
    const float* __restrict__ Wfc, const float* __restrict__ b_fc,
    float* __restrict__ out,
    unsigned short* __restrict__ Mt0, unsigned short* __restrict__ Mt1,
    const unsigned short* __restrict__ WihB, const unsigned short* __restrict__ WhhB,
    const unsigned short* __restrict__ WhT, const unsigned short* __restrict__ WcT,
    unsigned int* __restrict__ bar) {

  extern __shared__ char smem[];
  unsigned short* As   = (unsigned short*)(smem + OFF_AS);
  float* red           = (float*)(smem + OFF_RED);
  float* gatesLds      = (float*)(smem + OFF_RED);   // alias: red dead once inpB written
  unsigned short* inpB = (unsigned short*)(smem + OFF_INPB);
  unsigned short* hB   = (unsigned short*)(smem + OFF_HB);
  unsigned short* hnB  = (unsigned short*)(smem + OFF_HNB);
  unsigned short* cnB  = (unsigned short*)(smem + OFF_CNB);
  float* xLds          = (float*)(smem + OFF_XL);

  const int tid  = threadIdx.x;
  const int wave = tid >> 6;
  const int lane = tid & 63;
  const int l15  = lane & 15;
  const int quad = lane >> 4;
  const int row0 = blockIdx.x << 4;
  const int rr   = tid >> 5;     // 0..15
  const int kk_  = tid & 31;     // 0..31

  // ---- phase 0: stage A-slice -> LDS bf16 (block-local) ----
  {
    const fx4* Arow = (const fx4*)(A + (size_t)row0 * N_NODES);
    for (int i = tid; i < 16 * (N_NODES / 4); i += NTHREADS) {
      fx4 v = Arow[i];
      us4 o; o.x = f2bf(v.x); o.y = f2bf(v.y); o.z = f2bf(v.z); o.w = f2bf(v.w);
      int r = i >> 10, c = (i & 1023) << 2;
      *(us4*)(As + r * A_STRIDE + c) = o;
    }
  }
  float h_reg = 0.f, c_reg = 0.f;
  __syncthreads();

  for (int t = 0; t < ROLLS; ++t) {
    const unsigned short* Mi = (t & 1) ? Mt1 : Mt0;
    unsigned short* Mo       = (t & 1) ? Mt0 : Mt1;

    hB[rr * 48 + kk_] = f2bf(h_reg);
    if (t + 1 < ROLLS && tid < 128) {
      int r2 = tid >> 3, f = tid & 7;
      if (f < F_INPUT)
        xLds[r2 * 8 + f] = X[(size_t)(t + 1) * N_NODES * F_INPUT + (size_t)(row0 + r2) * F_INPUT + f];
    }

    // ---- split-K MFMA: inp(16x32) = A(16x4096)@M(4096x32); wave w owns K-chunk 512 ----
    fx4 acc0 = {0.f,0.f,0.f,0.f}, acc1 = {0.f,0.f,0.f,0.f};
    {
      const unsigned short* Al = As + l15 * A_STRIDE + wave * 512 + quad * 8;
      const unsigned short* B0 = Mi + (size_t)l15 * N_NODES        + wave * 512 + quad * 8;
      const unsigned short* B1 = Mi + (size_t)(16 + l15) * N_NODES + wave * 512 + quad * 8;
#pragma unroll
      for (int kk = 0; kk < 16; ++kk) {
        bf16x8 a  = *(const bf16x8*)(Al + kk * 32);
        bf16x8 b0 = *(const bf16x8*)(B0 + kk * 32);
        bf16x8 b1 = *(const bf16x8*)(B1 + kk * 32);
        acc0 = __builtin_amdgcn_mfma_f32_16x16x32_bf16(a, b0, acc0, 0, 0, 0);
        acc1 = __builtin_amdgcn_mfma_f32_16x16x32_bf16(a, b1, acc1, 0, 0, 0);
      }
    }
#pragma unroll
    for (int r = 0; r < 4; ++r) {   // C-layout: row = quad*4+r, col = l15
      red[(wave * 16 + quad * 4 + r) * 33 + l15]      = acc0[r];
      red[(wave * 16 + quad * 4 + r) * 33 + 16 + l15] = acc1[r];
    }
    __syncthreads();

    // reduce 8 partials -> inp bf16 (A-frag layout)
    {
      float s = 0.f;
#pragma unroll
      for (int w = 0; w < 8; ++w) s += red[(w * 16 + rr) * 33 + kk_];
      inpB[rr * 48 + kk_] = f2bf(s);
    }
    __syncthreads();

    // ---- gates(16x128) = inp@Wih^T + h@Whh^T + b; wave w owns gate cols [16w,16w+16) ----
    {
      int g = (wave << 4) + l15;
      bf16x8 aI = *(const bf16x8*)(inpB + l15 * 48 + quad * 8);
      bf16x8 aH = *(const bf16x8*)(hB   + l15 * 48 + quad * 8);
      bf16x8 bI = *(const bf16x8*)(WihB + g * 32 + quad * 8);
      bf16x8 bH = *(const bf16x8*)(WhhB + g * 32 + quad * 8);
      fx4 gacc = {0.f,0.f,0.f,0.f};
      gacc = __builtin_amdgcn_mfma_f32_16x16x32_bf16(aI, bI, gacc, 0, 0, 0);
      gacc = __builtin_amdgcn_mfma_f32_16x16x32_bf16(aH, bH, gacc, 0, 0, 0);
      float bias = b_ih[g] + b_hh[g];
#pragma unroll
      for (int r = 0; r < 4; ++r) gatesLds[(quad * 4 + r) * 132 + g] = gacc[r] + bias;
    }
    __syncthreads();

    // ---- LSTM cell elementwise; state in registers ----
    {
      float gi = gatesLds[rr * 132 + kk_];
      float gf = gatesLds[rr * 132 + 32 + kk_];
      float gg = gatesLds[rr * 132 + 64 + kk_];
      float go = gatesLds[rr * 132 + 96 + kk_];
      float i_ = 1.f / (1.f + __expf(-gi));
      float f_ = 1.f / (1.f + __expf(-gf));
      float g_ = tanhf(gg);
      float o_ = 1.f / (1.f + __expf(-go));
      float cn = f_ * c_reg + i_ * g_;
      float hn = o_ * tanhf(cn);
      c_reg = cn; h_reg = hn;
      hnB[rr * 48 + kk_] = f2bf(hn);
      cnB[rr * 48 + kk_] = f2bf(cn);
    }
    if (t == ROLLS - 1) break;
    __syncthreads();

    // ---- M_next = h_new@Wh + c_new@Wc + x@Wx; waves 0-1, direct global us4 store ----
    if (wave < 2) {
      int n = (wave << 4) + l15;
      bf16x8 aH = *(const bf16x8*)(hnB + l15 * 48 + quad * 8);
      bf16x8 aC = *(const bf16x8*)(cnB + l15 * 48 + quad * 8);
      bf16x8 bH = *(const bf16x8*)(WhT + n * 32 + quad * 8);
      bf16x8 bC = *(const bf16x8*)(WcT + n * 32 + quad * 8);
      fx4 m4 = {0.f,0.f,0.f,0.f};
      m4 = __builtin_amdgcn_mfma_f32_16x16x32_bf16(aH, bH, m4, 0, 0, 0);
      m4 = __builtin_amdgcn_mfma_f32_16x16x32_bf16(aC, bC, m4, 0, 0, 0);
      us4 o;
#pragma unroll
      for (int r = 0; r < 4; ++r) {
        int m = quad * 4 + r;
        float xs = m4[r];
#pragma unroll
        for (int f = 0; f < F_INPUT; ++f) xs += xLds[m * 8 + f] * Wx[f * H_DIM + n];
        o[r] = f2bf(xs);
      }
      *(us4*)(Mo + (size_t)n * N_NODES + row0 + quad * 4) = o;   // Mt[n][row0+m]
    }

    // ---- flag-tree grid barrier: arrive(own line) -> master gather -> go(8 lines) ----
    __syncthreads();   // drains every wave's Mo stores (vmcnt(0) before s_barrier)
    const unsigned int tgt = (unsigned int)(t + 1);
    if (tid == 0) {
      __builtin_amdgcn_fence(__ATOMIC_RELEASE, "agent");           // one buffer_wbl2
      __hip_atomic_store(&bar[BAR_ARRIVE(blockIdx.x)], tgt,
                         __ATOMIC_RELAXED, __HIP_MEMORY_SCOPE_AGENT);
    }
    if (blockIdx.x == 0) {
      if (tid < NBLOCKS) {
        while (__hip_atomic_load(&bar[BAR_ARRIVE(tid)],
                                 __ATOMIC_RELAXED, __HIP_MEMORY_SCOPE_AGENT) < tgt) {}
      }
      __syncthreads();                 // all 256 arrives observed
      if (tid < 8)
        __hip_atomic_store(&bar[BAR_GO(tid)], tgt,
                           __ATOMIC_RELAXED, __HIP_MEMORY_SCOPE_AGENT);
    }
    if (tid == 0) {
      while (__hip_atomic_load(&bar[BAR_GO(blockIdx.x & 7)],
                               __ATOMIC_RELAXED, __HIP_MEMORY_SCOPE_AGENT) < tgt)
        __builtin_amdgcn_s_sleep(1);
      __builtin_amdgcn_fence(__ATOMIC_ACQUIRE, "agent");           // one buffer_inv
    }
    __syncthreads();
  }

  // ---- final: out = h @ Wfc^T + b_fc ----
  {
    float v = h_reg * Wfc[kk_];
    v += __shfl_xor(v, 16);
    v += __shfl_xor(v, 8);
    v += __shfl_xor(v, 4);
    v += __shfl_xor(v, 2);
    v += __shfl_xor(v, 1);
    if (kk_ == 0) out[row0 + rr] = v + b_fc[0];
  }
}

extern "C" void kernel_launch(void* const* d_in, const int* in_sizes, int n_in,
                              void* d_out, int out_size, void* d_ws, size_t ws_size,
                              hipStream_t stream) {
  (void)in_sizes; (void)n_in; (void)out_size; (void)ws_size;
  const float* X   = (const float*)d_in[0];
  const float* A   = (const float*)d_in[1];
  const float* Wx  = (const float*)d_in[2];
  const float* Wh  = (const float*)d_in[3];
  const float* Wc  = (const float*)d_in[4];
  const float* Wih = (const float*)d_in[5];
  const float* Whh = (const float*)d_in[6];
  const float* bih = (const float*)d_in[7];
  const float* bhh = (const float*)d_in[8];
  const float* Wfc = (const float*)d_in[9];
  const float* bfc = (const float*)d_in[10];
  float* out = (float*)d_out;

  char* ws = (char*)d_ws;
  unsigned short* Mt0  = (unsigned short*)ws; ws += (size_t)N_NODES * H_DIM * 2;
  unsigned short* Mt1  = (unsigned short*)ws; ws += (size_t)N_NODES * H_DIM * 2;
  unsigned short* WihB = (unsigned short*)ws; ws += 128 * 32 * 2;
  unsigned short* WhhB = (unsigned short*)ws; ws += 128 * 32 * 2;
  unsigned short* WhT  = (unsigned short*)ws; ws += 32 * 32 * 2;
  unsigned short* WcT  = (unsigned short*)ws; ws += 32 * 32 * 2;
  ws = (char*)(((size_t)ws + 255) & ~(size_t)255);
  unsigned int* bar    = (unsigned int*)ws;   ws += BAR_UINTS * 4;

  hipLaunchKernelGGL(k_init, dim3(512), dim3(256), 0, stream,
                     X, Wx, Wih, Whh, Wh, Wc, Mt0, WihB, WhhB, WhT, WcT, bar);

  hipFuncSetAttribute((const void*)k_persist,
                      hipFuncAttributeMaxDynamicSharedMemorySize, LDS_TOTAL);

  void* args[] = {
    (void*)&X, (void*)&A, (void*)&Wx,
    (void*)&bih, (void*)&bhh, (void*)&Wfc, (void*)&bfc, (void*)&out,
    (void*)&Mt0, (void*)&Mt1, (void*)&WihB, (void*)&WhhB, (void*)&WhT, (void*)&WcT,
    (void*)&bar
  };
  hipLaunchCooperativeKernel((const void*)k_persist, dim3(NBLOCKS), dim3(NTHREADS),
                             args, LDS_TOTAL, stream);
}

// Round 6
// 3517.534 us; speedup vs baseline: 4.5011x; 1.1935x over previous
//
#include <hip/hip_runtime.h>

#define N_NODES 4096
#define H_DIM 32
#define F_INPUT 5
#define ROLLS 200
#define NBLOCKS 256
#define NTHREADS 512
#define A_STRIDE 4104   // 4096 + 8-element pad

// dynamic-LDS byte offsets (all 16B-aligned)
#define OFF_AS   0                  // A-slice bf16: 16 x 4104 x 2 = 131328
#define OFF_RED  131328             // split-K partials 8x16x33 f32 = 16896 (aliased by gatesLds 16x132 f32)
#define OFF_INPB 148224             // 16x48 bf16 = 1536
#define OFF_HB   149760
#define OFF_HNB  151296
#define OFF_CNB  152832
#define OFF_XL   154368             // 16x8 f32 = 512
#define LDS_TOTAL 154880

// barrier layout in uints (128B stride per flag line)
#define BAR_ARRIVE(b) ((b) * 32)
#define BAR_GO(g)     ((NBLOCKS + (g)) * 32)
#define BAR_UINTS     ((NBLOCKS + 8) * 32)

typedef __attribute__((ext_vector_type(8))) short bf16x8;
typedef __attribute__((ext_vector_type(4))) float fx4;
typedef __attribute__((ext_vector_type(4))) unsigned short us4;
typedef unsigned long long u64;

struct U128 { u64 a, b; };

__device__ __forceinline__ unsigned short f2bf(float f) {
  unsigned int u = __builtin_bit_cast(unsigned int, f);
  u += 0x7fffu + ((u >> 16) & 1u);   // RNE; inputs benign (no NaN/inf)
  return (unsigned short)(u >> 16);
}

// device-coherent 16B load: two relaxed agent-scope u64 atomic loads (sc-flagged,
// read at the coherent point -> no buffer_inv needed anywhere)
__device__ __forceinline__ bf16x8 ld_coh16(const unsigned short* p) {
  const u64* q = (const u64*)p;
  u64 lo = __hip_atomic_load(q,     __ATOMIC_RELAXED, __HIP_MEMORY_SCOPE_AGENT);
  u64 hi = __hip_atomic_load(q + 1, __ATOMIC_RELAXED, __HIP_MEMORY_SCOPE_AGENT);
  U128 u{lo, hi};
  return __builtin_bit_cast(bf16x8, u);
}

// ---- setup kernel (kernel-boundary visibility for all one-time data) ----
__global__ void k_init(const float* __restrict__ X, const float* __restrict__ Wx,
                       const float* __restrict__ Wih, const float* __restrict__ Whh,
                       const float* __restrict__ Wh, const float* __restrict__ Wc,
                       unsigned short* __restrict__ Mt0,
                       unsigned short* __restrict__ WihB, unsigned short* __restrict__ WhhB,
                       unsigned short* __restrict__ WhT, unsigned short* __restrict__ WcT,
                       unsigned int* __restrict__ bar) {
  int idx = blockIdx.x * 256 + threadIdx.x;      // grid 512*256 = 131072 = N*H exactly
  int k = idx >> 12;         // 0..31
  int row = idx & 4095;
  float s = 0.f;
#pragma unroll
  for (int f = 0; f < F_INPUT; ++f) s += X[row * F_INPUT + f] * Wx[f * H_DIM + k];
  Mt0[(size_t)k * N_NODES + row] = f2bf(s);
  if (idx < 4096) { WihB[idx] = f2bf(Wih[idx]); WhhB[idx] = f2bf(Whh[idx]); }
  if (idx < 1024) {
    int a = idx >> 5, b = idx & 31;
    WhT[a * 32 + b] = f2bf(Wh[b * 32 + a]);   // WhT[n][j] = Wh[j][n]
    WcT[a * 32 + b] = f2bf(Wc[b * 32 + a]);
  }
  if (idx < BAR_UINTS) bar[idx] = 0u;     // zero all flag lines every call (ws re-poisoned)
}

__global__ __launch_bounds__(NTHREADS, 2) void k_persist(
    const float* __restrict__ X, const float* __restrict__ A,
    const float* __restrict__ Wx,
    const float* __restrict__ b_ih, const float* __restrict__ b_hh,
    const float* __restrict__ Wfc, const float* __restrict__ b_fc,
    float* __restrict__ out,
    unsigned short* __restrict__ Mt0, unsigned short* __restrict__ Mt1,
    const unsigned short* __restrict__ WihB, const unsigned short* __restrict__ WhhB,
    const unsigned short* __restrict__ WhT, const unsigned short* __restrict__ WcT,
    unsigned int* __restrict__ bar) {

  extern __shared__ char smem[];
  unsigned short* As   = (unsigned short*)(smem + OFF_AS);
  float* red           = (float*)(smem + OFF_RED);
  float* gatesLds      = (float*)(smem + OFF_RED);   // alias: red dead once inpB written
  unsigned short* inpB = (unsigned short*)(smem + OFF_INPB);
  unsigned short* hB   = (unsigned short*)(smem + OFF_HB);
  unsigned short* hnB  = (unsigned short*)(smem + OFF_HNB);
  unsigned short* cnB  = (unsigned short*)(smem + OFF_CNB);
  float* xLds          = (float*)(smem + OFF_XL);

  const int tid  = threadIdx.x;
  const int wave = tid >> 6;
  const int lane = tid & 63;
  const int l15  = lane & 15;
  const int quad = lane >> 4;
  const int row0 = blockIdx.x << 4;
  const int rr   = tid >> 5;     // 0..15
  const int kk_  = tid & 31;     // 0..31

  // ---- phase 0: stage A-slice -> LDS bf16 (block-local) ----
  {
    const fx4* Arow = (const fx4*)(A + (size_t)row0 * N_NODES);
    for (int i = tid; i < 16 * (N_NODES / 4); i += NTHREADS) {
      fx4 v = Arow[i];
      us4 o; o.x = f2bf(v.x); o.y = f2bf(v.y); o.z = f2bf(v.z); o.w = f2bf(v.w);
      int r = i >> 10, c = (i & 1023) << 2;
      *(us4*)(As + r * A_STRIDE + c) = o;
    }
  }
  float h_reg = 0.f, c_reg = 0.f;
  __syncthreads();

  for (int t = 0; t < ROLLS; ++t) {
    const unsigned short* Mi = (t & 1) ? Mt1 : Mt0;
    unsigned short* Mo       = (t & 1) ? Mt0 : Mt1;

    hB[rr * 48 + kk_] = f2bf(h_reg);
    if (t + 1 < ROLLS && tid < 128) {
      int r2 = tid >> 3, f = tid & 7;
      if (f < F_INPUT)
        xLds[r2 * 8 + f] = X[(size_t)(t + 1) * N_NODES * F_INPUT + (size_t)(row0 + r2) * F_INPUT + f];
    }

    // ---- split-K MFMA: inp(16x32) = A(16x4096)@M(4096x32); wave w owns K-chunk 512 ----
    // A from LDS (b128); M via device-coherent u64-pair loads (no inv needed)
    fx4 acc0 = {0.f,0.f,0.f,0.f}, acc1 = {0.f,0.f,0.f,0.f};
    {
      const unsigned short* Al = As + l15 * A_STRIDE + wave * 512 + quad * 8;
      const unsigned short* B0 = Mi + (size_t)l15 * N_NODES        + wave * 512 + quad * 8;
      const unsigned short* B1 = Mi + (size_t)(16 + l15) * N_NODES + wave * 512 + quad * 8;
#pragma unroll
      for (int kk = 0; kk < 16; ++kk) {
        bf16x8 a  = *(const bf16x8*)(Al + kk * 32);
        bf16x8 b0 = ld_coh16(B0 + kk * 32);
        bf16x8 b1 = ld_coh16(B1 + kk * 32);
        acc0 = __builtin_amdgcn_mfma_f32_16x16x32_bf16(a, b0, acc0, 0, 0, 0);
        acc1 = __builtin_amdgcn_mfma_f32_16x16x32_bf16(a, b1, acc1, 0, 0, 0);
      }
    }
#pragma unroll
    for (int r = 0; r < 4; ++r) {   // C-layout: row = quad*4+r, col = l15
      red[(wave * 16 + quad * 4 + r) * 33 + l15]      = acc0[r];
      red[(wave * 16 + quad * 4 + r) * 33 + 16 + l15] = acc1[r];
    }
    __syncthreads();

    // reduce 8 partials -> inp bf16 (A-frag layout)
    {
      float s = 0.f;
#pragma unroll
      for (int w = 0; w < 8; ++w) s += red[(w * 16 + rr) * 33 + kk_];
      inpB[rr * 48 + kk_] = f2bf(s);
    }
    __syncthreads();

    // ---- gates(16x128) = inp@Wih^T + h@Whh^T + b; wave w owns gate cols [16w,16w+16) ----
    {
      int g = (wave << 4) + l15;
      bf16x8 aI = *(const bf16x8*)(inpB + l15 * 48 + quad * 8);
      bf16x8 aH = *(const bf16x8*)(hB   + l15 * 48 + quad * 8);
      bf16x8 bI = *(const bf16x8*)(WihB + g * 32 + quad * 8);
      bf16x8 bH = *(const bf16x8*)(WhhB + g * 32 + quad * 8);
      fx4 gacc = {0.f,0.f,0.f,0.f};
      gacc = __builtin_amdgcn_mfma_f32_16x16x32_bf16(aI, bI, gacc, 0, 0, 0);
      gacc = __builtin_amdgcn_mfma_f32_16x16x32_bf16(aH, bH, gacc, 0, 0, 0);
      float bias = b_ih[g] + b_hh[g];
#pragma unroll
      for (int r = 0; r < 4; ++r) gatesLds[(quad * 4 + r) * 132 + g] = gacc[r] + bias;
    }
    __syncthreads();

    // ---- LSTM cell elementwise; state in registers ----
    {
      float gi = gatesLds[rr * 132 + kk_];
      float gf = gatesLds[rr * 132 + 32 + kk_];
      float gg = gatesLds[rr * 132 + 64 + kk_];
      float go = gatesLds[rr * 132 + 96 + kk_];
      float i_ = 1.f / (1.f + __expf(-gi));
      float f_ = 1.f / (1.f + __expf(-gf));
      float g_ = tanhf(gg);
      float o_ = 1.f / (1.f + __expf(-go));
      float cn = f_ * c_reg + i_ * g_;
      float hn = o_ * tanhf(cn);
      c_reg = cn; h_reg = hn;
      hnB[rr * 48 + kk_] = f2bf(hn);
      cnB[rr * 48 + kk_] = f2bf(cn);
    }
    if (t == ROLLS - 1) break;
    __syncthreads();

    // ---- M_next = h_new@Wh + c_new@Wc + x@Wx; waves 0-1, coherent u64 store ----
    if (wave < 2) {
      int n = (wave << 4) + l15;
      bf16x8 aH = *(const bf16x8*)(hnB + l15 * 48 + quad * 8);
      bf16x8 aC = *(const bf16x8*)(cnB + l15 * 48 + quad * 8);
      bf16x8 bH = *(const bf16x8*)(WhT + n * 32 + quad * 8);
      bf16x8 bC = *(const bf16x8*)(WcT + n * 32 + quad * 8);
      fx4 m4 = {0.f,0.f,0.f,0.f};
      m4 = __builtin_amdgcn_mfma_f32_16x16x32_bf16(aH, bH, m4, 0, 0, 0);
      m4 = __builtin_amdgcn_mfma_f32_16x16x32_bf16(aC, bC, m4, 0, 0, 0);
      us4 o;
#pragma unroll
      for (int r = 0; r < 4; ++r) {
        int m = quad * 4 + r;
        float xs = m4[r];
#pragma unroll
        for (int f = 0; f < F_INPUT; ++f) xs += xLds[m * 8 + f] * Wx[f * H_DIM + n];
        o[r] = f2bf(xs);
      }
      // write-through at agent scope: visible at coherent point once vmcnt drains
      __hip_atomic_store((u64*)(Mo + (size_t)n * N_NODES + row0 + quad * 4),
                         __builtin_bit_cast(u64, o),
                         __ATOMIC_RELAXED, __HIP_MEMORY_SCOPE_AGENT);
    }

    // ---- flag-tree grid barrier (no cache-maintenance fences) ----
    // __syncthreads drains every wave's vmcnt -> all sc1 Mo stores are at the
    // coherent point before any thread proceeds; flags themselves are agent-scope.
    __syncthreads();
    const unsigned int tgt = (unsigned int)(t + 1);
    if (tid == 0) {
      __hip_atomic_store(&bar[BAR_ARRIVE(blockIdx.x)], tgt,
                         __ATOMIC_RELAXED, __HIP_MEMORY_SCOPE_AGENT);
    }
    if (blockIdx.x == 0) {
      if (tid < NBLOCKS) {
        while (__hip_atomic_load(&bar[BAR_ARRIVE(tid)],
                                 __ATOMIC_RELAXED, __HIP_MEMORY_SCOPE_AGENT) < tgt) {}
      }
      __syncthreads();                 // all 256 arrives observed
      if (tid < 8)
        __hip_atomic_store(&bar[BAR_GO(tid)], tgt,
                           __ATOMIC_RELAXED, __HIP_MEMORY_SCOPE_AGENT);
    }
    if (tid == 0) {
      while (__hip_atomic_load(&bar[BAR_GO(blockIdx.x & 7)],
                               __ATOMIC_RELAXED, __HIP_MEMORY_SCOPE_AGENT) < tgt)
        __builtin_amdgcn_s_sleep(1);
    }
    __syncthreads();
  }

  // ---- final: out = h @ Wfc^T + b_fc ----
  {
    float v = h_reg * Wfc[kk_];
    v += __shfl_xor(v, 16);
    v += __shfl_xor(v, 8);
    v += __shfl_xor(v, 4);
    v += __shfl_xor(v, 2);
    v += __shfl_xor(v, 1);
    if (kk_ == 0) out[row0 + rr] = v + b_fc[0];
  }
}

extern "C" void kernel_launch(void* const* d_in, const int* in_sizes, int n_in,
                              void* d_out, int out_size, void* d_ws, size_t ws_size,
                              hipStream_t stream) {
  (void)in_sizes; (void)n_in; (void)out_size; (void)ws_size;
  const float* X   = (const float*)d_in[0];
  const float* A   = (const float*)d_in[1];
  const float* Wx  = (const float*)d_in[2];
  const float* Wh  = (const float*)d_in[3];
  const float* Wc  = (const float*)d_in[4];
  const float* Wih = (const float*)d_in[5];
  const float* Whh = (const float*)d_in[6];
  const float* bih = (const float*)d_in[7];
  const float* bhh = (const float*)d_in[8];
  const float* Wfc = (const float*)d_in[9];
  const float* bfc = (const float*)d_in[10];
  float* out = (float*)d_out;

  char* ws = (char*)d_ws;
  unsigned short* Mt0  = (unsigned short*)ws; ws += (size_t)N_NODES * H_DIM * 2;
  unsigned short* Mt1  = (unsigned short*)ws; ws += (size_t)N_NODES * H_DIM * 2;
  unsigned short* WihB = (unsigned short*)ws; ws += 128 * 32 * 2;
  unsigned short* WhhB = (unsigned short*)ws; ws += 128 * 32 * 2;
  unsigned short* WhT  = (unsigned short*)ws; ws += 32 * 32 * 2;
  unsigned short* WcT  = (unsigned short*)ws; ws += 32 * 32 * 2;
  ws = (char*)(((size_t)ws + 255) & ~(size_t)255);
  unsigned int* bar    = (unsigned int*)ws;   ws += BAR_UINTS * 4;

  hipLaunchKernelGGL(k_init, dim3(512), dim3(256), 0, stream,
                     X, Wx, Wih, Whh, Wh, Wc, Mt0, WihB, WhhB, WhT, WcT, bar);

  hipFuncSetAttribute((const void*)k_persist,
                      hipFuncAttributeMaxDynamicSharedMemorySize, LDS_TOTAL);

  void* args[] = {
    (void*)&X, (void*)&A, (void*)&Wx,
    (void*)&bih, (void*)&bhh, (void*)&Wfc, (void*)&bfc, (void*)&out,
    (void*)&Mt0, (void*)&Mt1, (void*)&WihB, (void*)&WhhB, (void*)&WhT, (void*)&WcT,
    (void*)&bar
  };
  hipLaunchCooperativeKernel((const void*)k_persist, dim3(NBLOCKS), dim3(NTHREADS),
                             args, LDS_TOTAL, stream);
}